// Round 1
// baseline (5229.229 us; speedup 1.0000x reference)
//
#include <hip/hip_runtime.h>

// Problem dims
#define NB    2
#define SEQ   512
#define NL    12
#define DIM   1024
#define NH    16
#define HD    64
#define DFF   4096
#define VOCAB 2048
#define CHD   7
#define NTOK  1024   // NB*SEQ

typedef __attribute__((ext_vector_type(4))) float f32x4;
typedef __attribute__((ext_vector_type(8))) short s16x8;
typedef __attribute__((ext_vector_type(4))) unsigned short u16x4;
typedef __attribute__((ext_vector_type(8))) unsigned short u16x8;

__device__ __forceinline__ unsigned short f2bf(float f) {
    unsigned u = __builtin_bit_cast(unsigned, f);
    u += 0x7fffu + ((u >> 16) & 1u);           // RNE
    return (unsigned short)(u >> 16);
}

// ---------------------------------------------------------------------------
// GEMM: C[M,N] = A[M,K] * B[K,N], f32 in/out, bf16 MFMA inside.
// grid: x = N/BN, y = M/BM, z = batch.
//   sBz != 0 : Bp = B0 + z*sBz (strided batch, used for w_out heads)
//   sBz == 0 : Bp = {B0,B1,B2}[z] (pointer-select, used for fused QKV / K-split)
//   kchunk   : K-split — this block handles A cols / B rows [z*kchunk, z*kchunk+K)
//   C index  = z*sCz + (r>>9)*rhi + (r&511)*ldc + c   (rhi=512*ldc for normal)
// ---------------------------------------------------------------------------
template<int BM, int BN>
__global__ __launch_bounds__(256)
void gemm_kernel(const float* __restrict__ A, const float* __restrict__ B0,
                 const float* __restrict__ B1, const float* __restrict__ B2,
                 float* __restrict__ C, int K, int lda, int ldb, int ldc,
                 int rhi, long sBz, long sCz, int kchunk)
{
    __shared__ unsigned short As[BM][40];   // [m][k], 80B rows (16B-aligned, pad)
    __shared__ unsigned short Bs[BN][40];   // [n][k] transposed

    const int tid = threadIdx.x;
    const int z   = blockIdx.z;
    const int m0  = blockIdx.y * BM;
    const int n0  = blockIdx.x * BN;

    const float* Bp = sBz ? (B0 + (long)z * sBz) : (z == 0 ? B0 : (z == 1 ? B1 : B2));
    const long koff = (long)z * kchunk;
    const float* Ap = A + koff;
    Bp += koff * (long)ldb;
    float* Cp = C + (long)z * sCz;

    const int w = tid >> 6, l = tid & 63;
    const int lrow = l & 15, lhi = l >> 4;
    const int wm = (w >> 1) * (BM / 2), wn = (w & 1) * (BN / 2);
    constexpr int FM = BM / 32, FN = BN / 32;
    constexpr int LB = (BN == 128) ? 7 : 6;

    f32x4 acc[FM][FN] = {};

    for (int k0 = 0; k0 < K; k0 += 32) {
        __syncthreads();
        // stage A tile BMx32 (coalesced float4), convert to bf16
        #pragma unroll
        for (int t = tid; t < BM * 8; t += 256) {
            int m = t >> 3, c4 = (t & 7) << 2;
            const float4 v = *reinterpret_cast<const float4*>(&Ap[(long)(m0 + m) * lda + k0 + c4]);
            u16x4 p = { f2bf(v.x), f2bf(v.y), f2bf(v.z), f2bf(v.w) };
            *reinterpret_cast<u16x4*>(&As[m][c4]) = p;
        }
        // stage B tile 32xBN transposed -> Bs[n][k]; scalar loads coalesced over n
        #pragma unroll
        for (int t = tid; t < BN * 8; t += 256) {
            int n = t & (BN - 1), kq = (t >> LB) << 2;
            long bb = (long)(k0 + kq) * ldb + n0 + n;
            float b0v = Bp[bb];
            float b1v = Bp[bb + ldb];
            float b2v = Bp[bb + 2 * (long)ldb];
            float b3v = Bp[bb + 3 * (long)ldb];
            u16x4 p = { f2bf(b0v), f2bf(b1v), f2bf(b2v), f2bf(b3v) };
            *reinterpret_cast<u16x4*>(&Bs[n][kq]) = p;
        }
        __syncthreads();

        s16x8 af[FM]; s16x8 bfr[FN];
        #pragma unroll
        for (int i = 0; i < FM; ++i)
            af[i] = __builtin_bit_cast(s16x8,
                *reinterpret_cast<const u16x8*>(&As[wm + i * 16 + lrow][lhi * 8]));
        #pragma unroll
        for (int j = 0; j < FN; ++j)
            bfr[j] = __builtin_bit_cast(s16x8,
                *reinterpret_cast<const u16x8*>(&Bs[wn + j * 16 + lrow][lhi * 8]));
        #pragma unroll
        for (int i = 0; i < FM; ++i)
            #pragma unroll
            for (int j = 0; j < FN; ++j)
                acc[i][j] = __builtin_amdgcn_mfma_f32_16x16x32_bf16(af[i], bfr[j], acc[i][j], 0, 0, 0);
    }

    // epilogue: D row = 4*lhi + e, col = lrow (m89-verified layout)
    #pragma unroll
    for (int i = 0; i < FM; ++i) {
        const int r0 = m0 + wm + i * 16 + lhi * 4;
        #pragma unroll
        for (int j = 0; j < FN; ++j) {
            const int c = n0 + wn + j * 16 + lrow;
            #pragma unroll
            for (int e = 0; e < 4; ++e) {
                const int r = r0 + e;
                const long idx = (long)(r >> 9) * rhi + (long)(r & 511) * ldc + c;
                Cp[idx] = acc[i][j][e];
            }
        }
    }
}

// dst[i] (+)= sum_z p[i + z*1M]   (K-split reduction), 1M elements
__global__ __launch_bounds__(256)
void reduce_add_kernel(float* __restrict__ dst, const float* __restrict__ p,
                       int nparts, int accum)
{
    const long i = ((long)blockIdx.x * 256 + threadIdx.x) * 4;
    f32x4 s;
    if (accum) s = *reinterpret_cast<const f32x4*>(&dst[i]);
    else       s = f32x4{0.f, 0.f, 0.f, 0.f};
    for (int zz = 0; zz < nparts; ++zz)
        s += *reinterpret_cast<const f32x4*>(&p[i + (long)zz * 1048576]);
    *reinterpret_cast<f32x4*>(&dst[i]) = s;
}

// concat [fused_input2 | primary_hidden] -> xcat[1024][2048]
__global__ __launch_bounds__(256)
void concat_kernel(const float* __restrict__ a, const float* __restrict__ b,
                   float* __restrict__ out)
{
    const long i = ((long)blockIdx.x * 256 + threadIdx.x) * 4;
    const int row = (int)(i >> 11), col = (int)(i & 2047);
    const float* src = (col < DIM) ? &a[(long)row * DIM + col]
                                   : &b[(long)row * DIM + col - DIM];
    *reinterpret_cast<f32x4*>(&out[i]) = *reinterpret_cast<const f32x4*>(src);
}

// RMSNorm: one block per row of 1024
__global__ __launch_bounds__(256)
void rms_kernel(const float* __restrict__ in, const float* __restrict__ w,
                float* __restrict__ out)
{
    __shared__ float red[4];
    const int row = blockIdx.x, tid = threadIdx.x;
    const long base = (long)row * DIM + tid * 4;
    f32x4 v = *reinterpret_cast<const f32x4*>(&in[base]);
    float ss = v[0]*v[0] + v[1]*v[1] + v[2]*v[2] + v[3]*v[3];
    for (int off = 32; off; off >>= 1) ss += __shfl_down(ss, off);
    if ((tid & 63) == 0) red[tid >> 6] = ss;
    __syncthreads();
    float s = red[0] + red[1] + red[2] + red[3];
    float r = 1.0f / sqrtf(s * (1.0f / DIM) + 1e-5f);
    f32x4 wv = *reinterpret_cast<const f32x4*>(&w[tid * 4]);
    f32x4 o = { v[0]*r*wv[0], v[1]*r*wv[1], v[2]*r*wv[2], v[3]*r*wv[3] };
    *reinterpret_cast<f32x4*>(&out[base]) = o;
}

// RoPE in-place on q and k. One thread per (b,s,h,i<32) pair.
__global__ __launch_bounds__(256)
void rope_kernel(float* __restrict__ q, float* __restrict__ k,
                 const int* __restrict__ pid)
{
    const int t = blockIdx.x * 256 + threadIdx.x;   // < 2*512*16*32
    const int i = t & 31, h = (t >> 5) & 15, s = (t >> 9) & 511, b = t >> 18;
    const int pos = pid[b * SEQ + s];
    const float invf = powf(10000.0f, -(float)i * (1.0f / 32.0f));
    const float ang = (float)pos * invf;
    const float c = cosf(ang), sn = sinf(ang);
    const long base = (((long)(b * SEQ + s)) * NH + h) * HD + i;
    float a1 = q[base], a2 = q[base + 32];
    q[base] = a1 * c - a2 * sn;  q[base + 32] = a2 * c + a1 * sn;
    float b1 = k[base], b2 = k[base + 32];
    k[base] = b1 * c - b2 * sn;  k[base + 32] = b2 * c + b1 * sn;
}

// v [b,s,h,d] -> vT [b,h,d,s]; grid (stile=8, bh=32)
__global__ __launch_bounds__(256)
void transpose_v_kernel(const float* __restrict__ v, float* __restrict__ vT)
{
    __shared__ float tile[64][65];
    const int st = blockIdx.x, bh = blockIdx.y, b = bh >> 4, h = bh & 15;
    const int s0 = st * 64;
    for (int t = threadIdx.x; t < 64 * 16; t += 256) {
        int s = t >> 4, c4 = (t & 15) * 4;
        f32x4 v4 = *reinterpret_cast<const f32x4*>(
            &v[(((long)(b * SEQ + s0 + s)) * NH + h) * HD + c4]);
        tile[s][c4] = v4[0]; tile[s][c4+1] = v4[1]; tile[s][c4+2] = v4[2]; tile[s][c4+3] = v4[3];
    }
    __syncthreads();
    for (int t = threadIdx.x; t < 64 * 16; t += 256) {
        int d = t >> 4, c4 = (t & 15) * 4;
        f32x4 o4 = { tile[c4][d], tile[c4+1][d], tile[c4+2][d], tile[c4+3][d] };
        *reinterpret_cast<f32x4*>(&vT[((long)bh * HD + d) * SEQ + s0 + c4]) = o4;
    }
}

// Flash-style causal attention; grid (qtile=8, bh=32), 4 waves, 64 q rows/block.
__global__ __launch_bounds__(256)
void attn_kernel(const float* __restrict__ q, const float* __restrict__ k,
                 const float* __restrict__ vT, float* __restrict__ att)
{
    __shared__ unsigned short Qs[64][72];  // [q][d]
    __shared__ unsigned short Ks[64][72];  // [t][d]
    __shared__ unsigned short Ps[64][72];  // [q][t]
    __shared__ unsigned short Vs[64][72];  // [d][t]
    const int tid = threadIdx.x;
    const int qt = blockIdx.x, bh = blockIdx.y, b = bh >> 4, h = bh & 15;
    const int q0 = qt * 64;
    const int w = tid >> 6, l = tid & 63, lrow = l & 15, lhi = l >> 4;

    for (int t = tid; t < 64 * 16; t += 256) {
        int r = t >> 4, c4 = (t & 15) * 4;
        f32x4 v4 = *reinterpret_cast<const f32x4*>(
            &q[(((long)(b * SEQ + q0 + r)) * NH + h) * HD + c4]);
        u16x4 p = { f2bf(v4[0]), f2bf(v4[1]), f2bf(v4[2]), f2bf(v4[3]) };
        *reinterpret_cast<u16x4*>(&Qs[r][c4]) = p;
    }

    float m_run[4], l_run[4];
    f32x4 o[4] = {};
    #pragma unroll
    for (int j = 0; j < 4; ++j) { m_run[j] = -1e30f; l_run[j] = 0.f; }
    const float scale = 0.125f;  // 1/sqrt(64)

    for (int kt = 0; kt <= qt; ++kt) {
        const int t0 = kt * 64;
        __syncthreads();
        for (int t = tid; t < 64 * 16; t += 256) {
            int r = t >> 4, c4 = (t & 15) * 4;
            f32x4 v4 = *reinterpret_cast<const f32x4*>(
                &k[(((long)(b * SEQ + t0 + r)) * NH + h) * HD + c4]);
            u16x4 p = { f2bf(v4[0]), f2bf(v4[1]), f2bf(v4[2]), f2bf(v4[3]) };
            *reinterpret_cast<u16x4*>(&Ks[r][c4]) = p;
        }
        for (int t = tid; t < 64 * 16; t += 256) {
            int d = t >> 4, c4 = (t & 15) * 4;
            f32x4 v4 = *reinterpret_cast<const f32x4*>(
                &vT[((long)bh * HD + d) * SEQ + t0 + c4]);
            u16x4 p = { f2bf(v4[0]), f2bf(v4[1]), f2bf(v4[2]), f2bf(v4[3]) };
            *reinterpret_cast<u16x4*>(&Vs[d][c4]) = p;
        }
        __syncthreads();

        // S = Q K^T, wave w owns rows [w*16, w*16+16)
        f32x4 s[4] = {};
        #pragma unroll
        for (int ks = 0; ks < 2; ++ks) {
            s16x8 aq = __builtin_bit_cast(s16x8,
                *reinterpret_cast<const u16x8*>(&Qs[w * 16 + lrow][ks * 32 + lhi * 8]));
            #pragma unroll
            for (int j = 0; j < 4; ++j) {
                s16x8 bk = __builtin_bit_cast(s16x8,
                    *reinterpret_cast<const u16x8*>(&Ks[j * 16 + lrow][ks * 32 + lhi * 8]));
                s[j] = __builtin_amdgcn_mfma_f32_16x16x32_bf16(aq, bk, s[j], 0, 0, 0);
            }
        }

        // online softmax (rows = lhi*4 + j, cols = tcol*16 + lrow)
        float pv[4][4], corr[4];
        #pragma unroll
        for (int j = 0; j < 4; ++j) {
            const int qrow = q0 + w * 16 + lhi * 4 + j;
            float sv[4], mx = -1e30f;
            #pragma unroll
            for (int tc = 0; tc < 4; ++tc) {
                const int tcur = t0 + tc * 16 + lrow;
                float vvv = s[tc][j] * scale;
                if (tcur > qrow) vvv = -1e30f;
                sv[tc] = vvv;
                mx = fmaxf(mx, vvv);
            }
            #pragma unroll
            for (int mk = 1; mk < 16; mk <<= 1) mx = fmaxf(mx, __shfl_xor(mx, mk));
            const float mnew = fmaxf(m_run[j], mx);
            const float c = __expf(m_run[j] - mnew);
            m_run[j] = mnew;
            float rs = 0.f;
            #pragma unroll
            for (int tc = 0; tc < 4; ++tc) {
                float p = __expf(sv[tc] - mnew);
                pv[tc][j] = p;
                rs += p;
            }
            #pragma unroll
            for (int mk = 1; mk < 16; mk <<= 1) rs += __shfl_xor(rs, mk);
            l_run[j] = l_run[j] * c + rs;
            corr[j] = c;
        }

        // P -> LDS (bf16); wave-local rows only
        #pragma unroll
        for (int tc = 0; tc < 4; ++tc)
            #pragma unroll
            for (int j = 0; j < 4; ++j)
                Ps[w * 16 + lhi * 4 + j][tc * 16 + lrow] = f2bf(pv[tc][j]);

        // rescale O, then O += P V
        #pragma unroll
        for (int dn = 0; dn < 4; ++dn)
            #pragma unroll
            for (int j = 0; j < 4; ++j)
                o[dn][j] *= corr[j];
        #pragma unroll
        for (int ks = 0; ks < 2; ++ks) {
            s16x8 ap = __builtin_bit_cast(s16x8,
                *reinterpret_cast<const u16x8*>(&Ps[w * 16 + lrow][ks * 32 + lhi * 8]));
            #pragma unroll
            for (int dn = 0; dn < 4; ++dn) {
                s16x8 bv = __builtin_bit_cast(s16x8,
                    *reinterpret_cast<const u16x8*>(&Vs[dn * 16 + lrow][ks * 32 + lhi * 8]));
                o[dn] = __builtin_amdgcn_mfma_f32_16x16x32_bf16(ap, bv, o[dn], 0, 0, 0);
            }
        }
    }

    #pragma unroll
    for (int dn = 0; dn < 4; ++dn)
        #pragma unroll
        for (int j = 0; j < 4; ++j) {
            const int qrow = q0 + w * 16 + lhi * 4 + j;
            const int d = dn * 16 + lrow;
            att[(((long)(b * SEQ + qrow)) * NH + h) * HD + d] = o[dn][j] / l_run[j];
        }
}

// g = silu(g) * u over 4M elements
__global__ __launch_bounds__(256)
void silu_mul_kernel(float* __restrict__ g, const float* __restrict__ u)
{
    const long i = ((long)blockIdx.x * 256 + threadIdx.x) * 4;
    f32x4 gv = *reinterpret_cast<const f32x4*>(&g[i]);
    f32x4 uv = *reinterpret_cast<const f32x4*>(&u[i]);
    f32x4 o;
    #pragma unroll
    for (int e = 0; e < 4; ++e) {
        float gx = gv[e];
        o[e] = gx / (1.0f + __expf(-gx)) * uv[e];
    }
    *reinterpret_cast<f32x4*>(&g[i]) = o;
}

// ---------------------------------------------------------------------------
extern "C" void kernel_launch(void* const* d_in, const int* in_sizes, int n_in,
                              void* d_out, int out_size, void* d_ws, size_t ws_size,
                              hipStream_t stream)
{
    const float* f2   = (const float*)d_in[0];
    const float* ph   = (const float*)d_in[1];
    // d_in[2] attn_mask: causal (t<=s) by construction — applied analytically
    const float* wbr  = (const float*)d_in[3];
    const float* ln1  = (const float*)d_in[4];
    const float* wq   = (const float*)d_in[5];
    const float* wk   = (const float*)d_in[6];
    const float* wv   = (const float*)d_in[7];
    const float* wo   = (const float*)d_in[8];
    const float* ln2  = (const float*)d_in[9];
    const float* wg   = (const float*)d_in[10];
    const float* wu   = (const float*)d_in[11];
    const float* wd   = (const float*)d_in[12];
    const float* nw   = (const float*)d_in[13];
    const float* wout = (const float*)d_in[14];
    const int*   pid  = (const int*)d_in[15];
    float* out = (float*)d_out;

    float* ws = (float*)d_ws;
    const long M1 = 1048576;          // 1M floats
    float* xcat = ws;                  // 2M
    float* h    = ws + 2 * M1;         // 1M
    float* x    = ws + 3 * M1;         // 1M
    float* q    = ws + 4 * M1;         // 1M  (q,k,v contiguous for fused QKV z-out)
    float* kb   = ws + 5 * M1;         // 1M
    float* v    = ws + 6 * M1;         // 1M
    float* vT   = ws + 7 * M1;         // 1M
    float* att  = ws + 8 * M1;         // 1M
    float* g    = ws + 9 * M1;         // 4M
    float* u    = ws + 13 * M1;        // 4M   -> total 68 MB

    dim3 blk(256);

    concat_kernel<<<2048, blk, 0, stream>>>(f2, ph, xcat);
    // bridge (K=2048, split 2) -> partials in g, reduce to h
    gemm_kernel<64,64><<<dim3(16,16,2), blk, 0, stream>>>(
        xcat, wbr, wbr, wbr, g, 1024, 2048, DIM, DIM, 512*DIM, 0, M1, 1024);
    reduce_add_kernel<<<1024, blk, 0, stream>>>(h, g, 2, 0);

    for (int i = 0; i < NL; ++i) {
        rms_kernel<<<1024, blk, 0, stream>>>(h, ln1 + (long)i * DIM, x);
        // fused QKV via z-pointer-select -> q,kb,v
        gemm_kernel<64,64><<<dim3(16,16,3), blk, 0, stream>>>(
            x, wq + (long)i*M1, wk + (long)i*M1, wv + (long)i*M1, q,
            1024, DIM, DIM, DIM, 512*DIM, 0, M1, 0);
        rope_kernel<<<2048, blk, 0, stream>>>(q, kb, pid);
        transpose_v_kernel<<<dim3(8,32), blk, 0, stream>>>(v, vT);
        attn_kernel<<<dim3(8,32), blk, 0, stream>>>(q, kb, vT, att);
        // wo (K=1024, split 2) -> partials in g, h += reduce
        gemm_kernel<64,64><<<dim3(16,16,2), blk, 0, stream>>>(
            att, wo + (long)i*M1, wo + (long)i*M1, wo + (long)i*M1, g,
            512, DIM, DIM, DIM, 512*DIM, 0, M1, 512);
        reduce_add_kernel<<<1024, blk, 0, stream>>>(h, g, 2, 1);

        rms_kernel<<<1024, blk, 0, stream>>>(h, ln2 + (long)i * DIM, x);
        gemm_kernel<64,128><<<dim3(32,16,1), blk, 0, stream>>>(
            x, wg + (long)i*4*M1, wg + (long)i*4*M1, wg + (long)i*4*M1, g,
            1024, DIM, DFF, DFF, 512*DFF, 0, 0, 0);
        gemm_kernel<64,128><<<dim3(32,16,1), blk, 0, stream>>>(
            x, wu + (long)i*4*M1, wu + (long)i*4*M1, wu + (long)i*4*M1, u,
            1024, DIM, DFF, DFF, 512*DFF, 0, 0, 0);
        silu_mul_kernel<<<4096, blk, 0, stream>>>(g, u);
        // down (K=4096, split 4) -> partials in u, h += reduce
        gemm_kernel<64,64><<<dim3(16,16,4), blk, 0, stream>>>(
            g, wd + (long)i*4*M1, wd + (long)i*4*M1, wd + (long)i*4*M1, u,
            1024, DFF, DIM, DIM, 512*DIM, 0, M1, 1024);
        reduce_add_kernel<<<1024, blk, 0, stream>>>(h, u, 4, 1);
    }

    rms_kernel<<<1024, blk, 0, stream>>>(h, nw, x);
    // heads: z=7 strided B, output (b, head, s, vocab) via rhi row remap
    gemm_kernel<64,128><<<dim3(16,16,7), blk, 0, stream>>>(
        x, wout, wout, wout, out,
        1024, DIM, VOCAB, VOCAB, CHD*512*VOCAB, (long)DIM*VOCAB, (long)512*VOCAB, 0);
}